// Round 10
// baseline (272.450 us; speedup 1.0000x reference)
//
#include <hip/hip_runtime.h>
#include <cstdint>
#include <cstddef>

// Problem dims (fixed by the reference): B=64, S=512, D=768, C=512
#define BB 64
#define SS 512
#define DD 768
#define CC 512

typedef __attribute__((ext_vector_type(8))) short short8;
typedef __attribute__((ext_vector_type(4))) float f32x4;

#define GLOBAL_AS __attribute__((address_space(1)))
#define LDS_AS __attribute__((address_space(3)))

// float -> bf16 bits, round-to-nearest-even
static __device__ __forceinline__ unsigned short f2bf(float f) {
  union { float f; unsigned u; } v; v.f = f;
  unsigned u = v.u;
  u += 0x7FFFu + ((u >> 16) & 1u);
  return (unsigned short)(u >> 16);
}

// async 16B/lane global->LDS copy (wave-uniform LDS base + lane*16)
static __device__ __forceinline__ void async_copy16(const void* g, void* l) {
  __builtin_amdgcn_global_load_lds((const GLOBAL_AS void*)g, (LDS_AS void*)l,
                                   16, 0, 0);
}

// ---------------------------------------------------------------------------
// Kernel 1: normalize label embeddings -> bf16, FRAGMENT-LINEAR layout.
// Per 16-class chunk (chunk = c>>4), element [class mr=c&15][d] is stored at
// ushort offset  chunk*12288 + kc*512 + q*128 + mr*8 + j   where
// kc = d>>5, q = (d>>3)&3, j = d&7.
// The 64 lanes of a wave reading MFMA B-fragments for K-slice kc then read
// 1024 CONSECUTIVE bytes (addr = lane*16 + kc*1024): zero bank conflicts
// (verified round 4: SQ_LDS_BANK_CONFLICT 6.29M -> 0).
// ---------------------------------------------------------------------------
__global__ __launch_bounds__(256) void k_label_norm(const float* __restrict__ L,
                                                    unsigned short* __restrict__ Lnb) {
  const int c = blockIdx.x;
  const int tid = threadIdx.x;
  const float* row = L + (size_t)c * DD;
  float v[3];
  float s = 0.f;
#pragma unroll
  for (int k = 0; k < 3; k++) { v[k] = row[tid + 256 * k]; s += v[k] * v[k]; }
#pragma unroll
  for (int o = 32; o > 0; o >>= 1) s += __shfl_xor(s, o, 64);
  __shared__ float wsum[4];
  if ((tid & 63) == 0) wsum[tid >> 6] = s;
  __syncthreads();
  const float tot = wsum[0] + wsum[1] + wsum[2] + wsum[3];
  const float inv = 1.f / fmaxf(sqrtf(tot), 1e-8f);
  unsigned short* ochunk = Lnb + (size_t)(c >> 4) * (16 * DD);
  const int mr = c & 15;
#pragma unroll
  for (int k = 0; k < 3; k++) {
    const int d = tid + 256 * k;
    const int kc = d >> 5;
    const int q = (d >> 3) & 3;
    const int j = d & 7;
    ochunk[kc * 512 + q * 128 + mr * 8 + j] = f2bf(v[k] * inv);
  }
}

// ---------------------------------------------------------------------------
// Kernel 2: partial max over HALF the classes, already norm-divided:
//   mpart[y][b,s] = max_{c in half y} cos(V[b,s,:], Ln[c,:])
//
// grid = dim3(512, 2): blockIdx.x = 64-token tile (SAME expression as the
// verified r4/r5 kernel -- no index decomposition), blockIdx.y = class half.
// Body is byte-identical to the r5-verified 128-VGPR/75.9us kernel except:
// two wave-uniform pointer adjustments at entry (chunks, mout -- pure SALU)
// and the chunk loop runs 16 instead of 32. NO launch_bounds pressure
// (r9 measured: it degrades codegen), no new per-lane values.
// VGPR gate: must report 128. Every 129+ variant (r3/r6/r7/r8/r9:
// 136/148/140/132/132) halved residency and lost.
// WHY the split: grid 1024 -> 3 blocks/CU materialize (vs 2 grid-capped);
// one block's __syncthreads vmcnt-drain hides under two other blocks'
// MFMA/LDS phases (m114 cross-block overlap). Cost: A loaded twice
// (L3-absorbed; r8 measured FETCH 106 MB at HBM 14%, harmless).
// ---------------------------------------------------------------------------
__global__ __launch_bounds__(256) void k_sims_max(const float* __restrict__ V,
                                                  const unsigned short* __restrict__ Lnb,
                                                  float* __restrict__ mpart) {
  const int tid = threadIdx.x;
  const int wave = tid >> 6;
  const int lane = tid & 63;
  const int q = lane >> 4;    // quad 0..3 (K-slice of the fragment)
  const int mr = lane & 15;   // row (token) for A, col (class) for B
  const int64_t tokBase = (int64_t)blockIdx.x * 64 + wave * 16;

  // class-half bases (wave-uniform, SALU): half y covers chunks y*16..y*16+15
  const unsigned short* chunks = Lnb + (size_t)blockIdx.y * (16 * 16 * DD);
  float* mout = mpart + (size_t)blockIdx.y * (BB * SS);

  __shared__ unsigned short Bs[2][16 * DD];  // 2 x 24576 B
  __shared__ float nrmS[4][16];

  // ---- prefetch class-chunk 0 into buf 0 (async, in flight during A load)
  {
    const char* src = (const char*)chunks;
    char* dst = (char*)&Bs[0][0];
#pragma unroll
    for (int i = wave; i < 24; i += 4)
      async_copy16(src + i * 1024 + lane * 16, dst + i * 1024);
  }

  // ---- load A fragments + squared norm
  const float* arow = V + (tokBase + mr) * DD + q * 8;
  short8 afrag[24];
  float nrm2 = 0.f;
#pragma unroll
  for (int kc = 0; kc < 24; kc++) {
    const float4* p = (const float4*)(arow + kc * 32);
    const float4 x = p[0];
    const float4 y = p[1];
    short8 a;
    a[0] = (short)f2bf(x.x); a[1] = (short)f2bf(x.y);
    a[2] = (short)f2bf(x.z); a[3] = (short)f2bf(x.w);
    a[4] = (short)f2bf(y.x); a[5] = (short)f2bf(y.y);
    a[6] = (short)f2bf(y.z); a[7] = (short)f2bf(y.w);
    afrag[kc] = a;
    nrm2 += x.x * x.x + x.y * x.y + x.z * x.z + x.w * x.w;
    nrm2 += y.x * y.x + y.y * y.y + y.z * y.z + y.w * y.w;
  }
  // lanes {m, m+16, m+32, m+48} each hold 1/4 of token m's sum of squares
  nrm2 += __shfl_xor(nrm2, 16, 64);
  nrm2 += __shfl_xor(nrm2, 32, 64);
  if (q == 0) nrmS[wave][mr] = nrm2;

  __syncthreads();  // buf0 staged (vmcnt drain) + nrmS visible

  const int laneByte = lane * 16;  // fragment-linear: lane's 16B within a K-slice
  f32x4 vmax = {-3e38f, -3e38f, -3e38f, -3e38f};
  for (int cc = 0; cc < 16; cc++) {
    const int p = cc & 1;
    // prefetch next chunk into the other buffer (its readers finished at the
    // barrier ending iteration cc-1)
    if (cc + 1 < 16) {
      const char* src = (const char*)(chunks + (size_t)(cc + 1) * 16 * DD);
      char* dst = (char*)&Bs[p ^ 1][0];
#pragma unroll
      for (int i = wave; i < 24; i += 4)
        async_copy16(src + i * 1024 + lane * 16, dst + i * 1024);
    }
    f32x4 acc = {0.f, 0.f, 0.f, 0.f};
    const char* bbase = (const char*)&Bs[p][0] + laneByte;
    // depth-4 rotating B-fragment pipeline (neutral r5, part of the verified
    // 128-VGPR allocation -- kept to minimize perturbation)
    short8 bf[4];
#pragma unroll
    for (int j = 0; j < 4; j++) bf[j] = *(const short8*)(bbase + j * 1024);
#pragma unroll
    for (int kc = 0; kc < 24; kc++) {
      acc = __builtin_amdgcn_mfma_f32_16x16x32_bf16(afrag[kc], bf[kc & 3], acc, 0, 0, 0);
      if (kc + 4 < 24) bf[kc & 3] = *(const short8*)(bbase + (kc + 4) * 1024);
    }
    vmax[0] = fmaxf(vmax[0], acc[0]);
    vmax[1] = fmaxf(vmax[1], acc[1]);
    vmax[2] = fmaxf(vmax[2], acc[2]);
    vmax[3] = fmaxf(vmax[3], acc[3]);
    __syncthreads();  // drains prefetch vmcnt + guards buffer reuse
  }
  // reduce max over the 16 column-lanes of each quad
#pragma unroll
  for (int o = 1; o < 16; o <<= 1) {
#pragma unroll
    for (int r = 0; r < 4; r++) vmax[r] = fmaxf(vmax[r], __shfl_xor(vmax[r], o, 64));
  }
  // rows held by this quad are tokens q*4 + r
  if (mr == 0) {
#pragma unroll
    for (int r = 0; r < 4; r++) {
      const float nr = nrmS[wave][q * 4 + r];
      mout[tokBase + q * 4 + r] = vmax[r] / fmaxf(sqrtf(nr), 1e-8f);
    }
  }
}

// ---------------------------------------------------------------------------
// Kernel 3: combine class-halves, then softmax over S per batch.
// grid = B blocks x 256 threads. (Verified r8/r9 variant.)
// ---------------------------------------------------------------------------
__global__ __launch_bounds__(256) void k_softmax(const float* __restrict__ mpart,
                                                 float* __restrict__ beta) {
  const int b = blockIdx.x;
  const int tid = threadIdx.x;
  const size_t i0 = (size_t)b * SS + tid;
  const size_t i1 = i0 + 256;
  const float v0 = fmaxf(mpart[i0], mpart[i0 + BB * SS]);
  const float v1 = fmaxf(mpart[i1], mpart[i1 + BB * SS]);
  float mx = fmaxf(v0, v1);
#pragma unroll
  for (int o = 32; o > 0; o >>= 1) mx = fmaxf(mx, __shfl_xor(mx, o, 64));
  __shared__ float wred[4];
  if ((tid & 63) == 0) wred[tid >> 6] = mx;
  __syncthreads();
  mx = fmaxf(fmaxf(wred[0], wred[1]), fmaxf(wred[2], wred[3]));
  const float e0 = __expf(v0 - mx);
  const float e1 = __expf(v1 - mx);
  float s = e0 + e1;
#pragma unroll
  for (int o = 32; o > 0; o >>= 1) s += __shfl_xor(s, o, 64);
  __syncthreads();  // wred reuse hazard
  if ((tid & 63) == 0) wred[tid >> 6] = s;
  __syncthreads();
  s = wred[0] + wred[1] + wred[2] + wred[3];
  const float inv = 1.f / s;
  float* bb = beta + (size_t)b * SS;
  bb[tid] = e0 * inv;
  bb[tid + 256] = e1 * inv;
}

// ---------------------------------------------------------------------------
// Kernel 4: partial z over (batch, s-chunk). grid = B*nsc x 192 threads.
// Thread owns one float4 of D; second (and last) full read of V, coalesced.
// ---------------------------------------------------------------------------
__global__ __launch_bounds__(192) void k_zpart(const float* __restrict__ V,
                                               const float* __restrict__ beta,
                                               float* __restrict__ zpart,
                                               int spc, int nsc) {
  const int blk = blockIdx.x;
  const int b = blk / nsc;
  const int sc = blk % nsc;
  const int tid = threadIdx.x;
  const float* vb = V + ((size_t)b * SS + (size_t)sc * spc) * DD + tid * 4;
  const float* bb = beta + (size_t)b * SS + (size_t)sc * spc;
  float4 acc = {0.f, 0.f, 0.f, 0.f};
#pragma unroll 4
  for (int s = 0; s < spc; s++) {
    const float w = bb[s];
    const float4 x = *(const float4*)(vb + (size_t)s * DD);
    acc.x += w * x.x; acc.y += w * x.y; acc.z += w * x.z; acc.w += w * x.w;
  }
  *(float4*)(zpart + (size_t)blk * DD + tid * 4) = acc;
}

// ---------------------------------------------------------------------------
// Kernel 5: reduce z-partials -> z (to out), then out = z @ fc_w^T + fc_b.
// grid = 2*B blocks (b, class-half) x 256 threads; fc_w L2/L3-resident.
// ---------------------------------------------------------------------------
__global__ __launch_bounds__(256) void k_final(const float* __restrict__ zpart,
                                               const float* __restrict__ fc_w,
                                               const float* __restrict__ fc_b,
                                               float* __restrict__ out,
                                               float* __restrict__ zout,
                                               int nsc) {
  const int b = blockIdx.x >> 1;
  const int half = blockIdx.x & 1;
  const int tid = threadIdx.x;
  __shared__ float zs[DD];
  for (int i = tid; i < DD; i += 256) {
    float s = 0.f;
    for (int sc = 0; sc < nsc; sc++) s += zpart[((size_t)b * nsc + sc) * DD + i];
    zs[i] = s;
    if (half == 0) zout[(size_t)b * DD + i] = s;
  }
  __syncthreads();
  const int c = half * 256 + tid;
  const float4* w = (const float4*)(fc_w + (size_t)c * DD);
  float acc = 0.f;
  for (int d4 = 0; d4 < DD / 4; d4++) {
    const float4 ww = w[d4];
    acc += ww.x * zs[d4 * 4] + ww.y * zs[d4 * 4 + 1] +
           ww.z * zs[d4 * 4 + 2] + ww.w * zs[d4 * 4 + 3];
  }
  out[(size_t)b * CC + c] = acc + fc_b[c];
}

// ---------------------------------------------------------------------------
extern "C" void kernel_launch(void* const* d_in, const int* in_sizes, int n_in,
                              void* d_out, int out_size, void* d_ws, size_t ws_size,
                              hipStream_t stream) {
  const float* V  = (const float*)d_in[0];  // [64,512,768]
  const float* L  = (const float*)d_in[1];  // [512,768]
  const float* fw = (const float*)d_in[2];  // [512,768]
  const float* fb = (const float*)d_in[3];  // [512]
  float* out = (float*)d_out;               // [64*512] out, then [64*768] z

  char* ws = (char*)d_ws;
  unsigned short* Lnb = (unsigned short*)ws;            // 786432 B (frag-linear)
  float* mpart = (float*)(ws + 786432);                 // 2 x 131072 B
  float* beta  = (float*)(ws + 1048576);                // 131072 B
  float* zpart = (float*)(ws + 1179648);                // nsc*64*768*4 B

  // 16 s-chunks if the workspace allows, else 8
  const int nsc = (ws_size >= (size_t)1179648 + (size_t)16 * BB * DD * 4) ? 16 : 8;
  const int spc = SS / nsc;

  k_label_norm<<<CC, 256, 0, stream>>>(L, Lnb);
  k_sims_max<<<dim3(512, 2), 256, 0, stream>>>(V, Lnb, mpart);
  k_softmax<<<BB, 256, 0, stream>>>(mpart, beta);
  k_zpart<<<BB * nsc, 192, 0, stream>>>(V, beta, zpart, spc, nsc);
  k_final<<<2 * BB, 256, 0, stream>>>(zpart, fw, fb, out, out + BB * CC, nsc);
}

// Round 11
// 239.830 us; speedup vs baseline: 1.1360x; 1.1360x over previous
//
#include <hip/hip_runtime.h>
#include <cstdint>
#include <cstddef>

// Problem dims (fixed by the reference): B=64, S=512, D=768, C=512
#define BB 64
#define SS 512
#define DD 768
#define CC 512

typedef __attribute__((ext_vector_type(8))) short short8;
typedef __attribute__((ext_vector_type(4))) float f32x4;

#define GLOBAL_AS __attribute__((address_space(1)))
#define LDS_AS __attribute__((address_space(3)))

// float -> bf16 bits, round-to-nearest-even
static __device__ __forceinline__ unsigned short f2bf(float f) {
  union { float f; unsigned u; } v; v.f = f;
  unsigned u = v.u;
  u += 0x7FFFu + ((u >> 16) & 1u);
  return (unsigned short)(u >> 16);
}

// async 16B/lane global->LDS copy (wave-uniform LDS base + lane*16)
static __device__ __forceinline__ void async_copy16(const void* g, void* l) {
  __builtin_amdgcn_global_load_lds((const GLOBAL_AS void*)g, (LDS_AS void*)l,
                                   16, 0, 0);
}

// ---------------------------------------------------------------------------
// Kernel 1: normalize label embeddings -> bf16, FRAGMENT-LINEAR layout.
// Per 16-class chunk (chunk = c>>4), element [class mr=c&15][d] is stored at
// ushort offset  chunk*12288 + kc*512 + q*128 + mr*8 + j   where
// kc = d>>5, q = (d>>3)&3, j = d&7.
// Wave reads of MFMA B-fragments for K-slice kc are then 1024 CONSECUTIVE
// bytes (addr = lane*16 + kc*1024): zero bank conflicts (verified r4:
// SQ_LDS_BANK_CONFLICT 6.29M -> 0).
// ---------------------------------------------------------------------------
__global__ __launch_bounds__(256) void k_label_norm(const float* __restrict__ L,
                                                    unsigned short* __restrict__ Lnb) {
  const int c = blockIdx.x;
  const int tid = threadIdx.x;
  const float* row = L + (size_t)c * DD;
  float v[3];
  float s = 0.f;
#pragma unroll
  for (int k = 0; k < 3; k++) { v[k] = row[tid + 256 * k]; s += v[k] * v[k]; }
#pragma unroll
  for (int o = 32; o > 0; o >>= 1) s += __shfl_xor(s, o, 64);
  __shared__ float wsum[4];
  if ((tid & 63) == 0) wsum[tid >> 6] = s;
  __syncthreads();
  const float tot = wsum[0] + wsum[1] + wsum[2] + wsum[3];
  const float inv = 1.f / fmaxf(sqrtf(tot), 1e-8f);
  unsigned short* ochunk = Lnb + (size_t)(c >> 4) * (16 * DD);
  const int mr = c & 15;
#pragma unroll
  for (int k = 0; k < 3; k++) {
    const int d = tid + 256 * k;
    const int kc = d >> 5;
    const int q = (d >> 3) & 3;
    const int j = d & 7;
    ochunk[kc * 512 + q * 128 + mr * 8 + j] = f2bf(v[k] * inv);
  }
}

// ---------------------------------------------------------------------------
// Kernel 2: m[b,s] = max_c dot(V[b,s,:], Ln[c,:]) / max(||V||,eps)
// EXACT r5-verified kernel (75.9 us, VGPR 128, occ ~20%, conflicts 0).
// 512 blocks x 4 waves x 16 tokens; afrag 96 VGPR; 2-buffer
// __syncthreads-drained global_load_lds staging; fragment-linear B reads.
// Post-r10 ledger: this structure is ~70% of its LDS-port+prologue floor
// (~55-60us); all occupancy/pipeline escapes are VGPR-cursed (128-cliff,
// n=5: r3/r6/r7/r8/r9/r10). Do not perturb.
// ---------------------------------------------------------------------------
__global__ __launch_bounds__(256) void k_sims_max(const float* __restrict__ V,
                                                  const unsigned short* __restrict__ Lnb,
                                                  float* __restrict__ m_out) {
  const int tid = threadIdx.x;
  const int wave = tid >> 6;
  const int lane = tid & 63;
  const int q = lane >> 4;    // quad 0..3 (K-slice of the fragment)
  const int mr = lane & 15;   // row (token) for A, col (class) for B
  const int64_t tokBase = (int64_t)blockIdx.x * 64 + wave * 16;

  __shared__ unsigned short Bs[2][16 * DD];  // 2 x 24576 B
  __shared__ float nrmS[4][16];

  // ---- prefetch class-chunk 0 into buf 0 (async, in flight during A load)
  {
    const char* src = (const char*)Lnb;
    char* dst = (char*)&Bs[0][0];
#pragma unroll
    for (int i = wave; i < 24; i += 4)
      async_copy16(src + i * 1024 + lane * 16, dst + i * 1024);
  }

  // ---- load A fragments + squared norm
  const float* arow = V + (tokBase + mr) * DD + q * 8;
  short8 afrag[24];
  float nrm2 = 0.f;
#pragma unroll
  for (int kc = 0; kc < 24; kc++) {
    const float4* p = (const float4*)(arow + kc * 32);
    const float4 x = p[0];
    const float4 y = p[1];
    short8 a;
    a[0] = (short)f2bf(x.x); a[1] = (short)f2bf(x.y);
    a[2] = (short)f2bf(x.z); a[3] = (short)f2bf(x.w);
    a[4] = (short)f2bf(y.x); a[5] = (short)f2bf(y.y);
    a[6] = (short)f2bf(y.z); a[7] = (short)f2bf(y.w);
    afrag[kc] = a;
    nrm2 += x.x * x.x + x.y * x.y + x.z * x.z + x.w * x.w;
    nrm2 += y.x * y.x + y.y * y.y + y.z * y.z + y.w * y.w;
  }
  // lanes {m, m+16, m+32, m+48} each hold 1/4 of token m's sum of squares
  nrm2 += __shfl_xor(nrm2, 16, 64);
  nrm2 += __shfl_xor(nrm2, 32, 64);
  if (q == 0) nrmS[wave][mr] = nrm2;

  __syncthreads();  // buf0 staged (vmcnt drain) + nrmS visible

  const int laneByte = lane * 16;  // fragment-linear: lane's 16B within a K-slice
  f32x4 vmax = {-3e38f, -3e38f, -3e38f, -3e38f};
  for (int cc = 0; cc < 32; cc++) {
    const int p = cc & 1;
    // prefetch next chunk into the other buffer (its readers finished at the
    // barrier ending iteration cc-1)
    if (cc + 1 < 32) {
      const char* src = (const char*)(Lnb + (size_t)(cc + 1) * 16 * DD);
      char* dst = (char*)&Bs[p ^ 1][0];
#pragma unroll
      for (int i = wave; i < 24; i += 4)
        async_copy16(src + i * 1024 + lane * 16, dst + i * 1024);
    }
    f32x4 acc = {0.f, 0.f, 0.f, 0.f};
    const char* bbase = (const char*)&Bs[p][0] + laneByte;
    // depth-4 rotating B-fragment pipeline (neutral, part of the verified
    // 128-VGPR allocation)
    short8 bf[4];
#pragma unroll
    for (int j = 0; j < 4; j++) bf[j] = *(const short8*)(bbase + j * 1024);
#pragma unroll
    for (int kc = 0; kc < 24; kc++) {
      acc = __builtin_amdgcn_mfma_f32_16x16x32_bf16(afrag[kc], bf[kc & 3], acc, 0, 0, 0);
      if (kc + 4 < 24) bf[kc & 3] = *(const short8*)(bbase + (kc + 4) * 1024);
    }
    vmax[0] = fmaxf(vmax[0], acc[0]);
    vmax[1] = fmaxf(vmax[1], acc[1]);
    vmax[2] = fmaxf(vmax[2], acc[2]);
    vmax[3] = fmaxf(vmax[3], acc[3]);
    __syncthreads();  // drains prefetch vmcnt + guards buffer reuse
  }
  // reduce max over the 16 column-lanes of each quad
#pragma unroll
  for (int o = 1; o < 16; o <<= 1) {
#pragma unroll
    for (int r = 0; r < 4; r++) vmax[r] = fmaxf(vmax[r], __shfl_xor(vmax[r], o, 64));
  }
  // rows held by this quad are tokens q*4 + r
  if (mr == 0) {
#pragma unroll
    for (int r = 0; r < 4; r++) {
      const float nr = nrmS[wave][q * 4 + r];
      m_out[tokBase + q * 4 + r] = vmax[r] / fmaxf(sqrtf(nr), 1e-8f);
    }
  }
}

// ---------------------------------------------------------------------------
// Kernel 3: fused softmax + partial z over (batch, s-chunk).
// grid = B*nsc x 192 threads. Each block recomputes the batch's softmax
// stats from m (512 floats, L2-hit, 2 cheap block reductions -- r2-verified
// pattern), then accumulates acc = sum_s exp(m_s - mx) * V[s] * inv.
// Removes the standalone softmax launch and the beta round-trip.
// ---------------------------------------------------------------------------
__global__ __launch_bounds__(192) void k_zpart(const float* __restrict__ V,
                                               const float* __restrict__ m,
                                               float* __restrict__ zpart,
                                               int spc, int nsc) {
  const int blk = blockIdx.x;
  const int b = blk / nsc;
  const int sc = blk % nsc;
  const int tid = threadIdx.x;
  const float* mb = m + (size_t)b * SS;

  // ---- softmax stats over the 512 m-values of batch b
  const float x0 = mb[tid];
  const float x1 = mb[tid + 192];
  const float x2 = (tid < 128) ? mb[tid + 384] : -3e38f;
  float mx = fmaxf(fmaxf(x0, x1), x2);
#pragma unroll
  for (int o = 32; o > 0; o >>= 1) mx = fmaxf(mx, __shfl_xor(mx, o, 64));
  __shared__ float redm[3];
  __shared__ float reds[3];
  if ((tid & 63) == 0) redm[tid >> 6] = mx;
  __syncthreads();
  mx = fmaxf(redm[0], fmaxf(redm[1], redm[2]));
  float es = __expf(x0 - mx) + __expf(x1 - mx) +
             ((tid < 128) ? __expf(x2 - mx) : 0.f);
#pragma unroll
  for (int o = 32; o > 0; o >>= 1) es += __shfl_xor(es, o, 64);
  if ((tid & 63) == 0) reds[tid >> 6] = es;
  __syncthreads();
  const float inv = 1.f / (reds[0] + reds[1] + reds[2]);

  // ---- weighted partial sum over this block's s-chunk
  const float* vb = V + ((size_t)b * SS + (size_t)sc * spc) * DD + tid * 4;
  const float* msc = mb + (size_t)sc * spc;
  float4 acc = {0.f, 0.f, 0.f, 0.f};
#pragma unroll 4
  for (int s = 0; s < spc; s++) {
    const float w = __expf(msc[s] - mx);
    const float4 x = *(const float4*)(vb + (size_t)s * DD);
    acc.x += w * x.x; acc.y += w * x.y; acc.z += w * x.z; acc.w += w * x.w;
  }
  acc.x *= inv; acc.y *= inv; acc.z *= inv; acc.w *= inv;
  *(float4*)(zpart + (size_t)blk * DD + tid * 4) = acc;
}

// ---------------------------------------------------------------------------
// Kernel 4: reduce z-partials -> z (to out), then out = z @ fc_w^T + fc_b.
// grid = 2*B blocks (b, class-half) x 256 threads; fc_w L2/L3-resident.
// ---------------------------------------------------------------------------
__global__ __launch_bounds__(256) void k_final(const float* __restrict__ zpart,
                                               const float* __restrict__ fc_w,
                                               const float* __restrict__ fc_b,
                                               float* __restrict__ out,
                                               float* __restrict__ zout,
                                               int nsc) {
  const int b = blockIdx.x >> 1;
  const int half = blockIdx.x & 1;
  const int tid = threadIdx.x;
  __shared__ float zs[DD];
  for (int i = tid; i < DD; i += 256) {
    float s = 0.f;
    for (int sc = 0; sc < nsc; sc++) s += zpart[((size_t)b * nsc + sc) * DD + i];
    zs[i] = s;
    if (half == 0) zout[(size_t)b * DD + i] = s;
  }
  __syncthreads();
  const int c = half * 256 + tid;
  const float4* w = (const float4*)(fc_w + (size_t)c * DD);
  float acc = 0.f;
  for (int d4 = 0; d4 < DD / 4; d4++) {
    const float4 ww = w[d4];
    acc += ww.x * zs[d4 * 4] + ww.y * zs[d4 * 4 + 1] +
           ww.z * zs[d4 * 4 + 2] + ww.w * zs[d4 * 4 + 3];
  }
  out[(size_t)b * CC + c] = acc + fc_b[c];
}

// ---------------------------------------------------------------------------
extern "C" void kernel_launch(void* const* d_in, const int* in_sizes, int n_in,
                              void* d_out, int out_size, void* d_ws, size_t ws_size,
                              hipStream_t stream) {
  const float* V  = (const float*)d_in[0];  // [64,512,768]
  const float* L  = (const float*)d_in[1];  // [512,768]
  const float* fw = (const float*)d_in[2];  // [512,768]
  const float* fb = (const float*)d_in[3];  // [512]
  float* out = (float*)d_out;               // [64*512] out, then [64*768] z

  char* ws = (char*)d_ws;
  unsigned short* Lnb = (unsigned short*)ws;            // 786432 B (frag-linear)
  float* m     = (float*)(ws + 786432);                 // 131072 B
  float* zpart = (float*)(ws + 917504);                 // nsc*64*768*4 B

  // 16 s-chunks if the workspace allows, else 8
  const int nsc = (ws_size >= (size_t)917504 + (size_t)16 * BB * DD * 4) ? 16 : 8;
  const int spc = SS / nsc;

  k_label_norm<<<CC, 256, 0, stream>>>(L, Lnb);
  k_sims_max<<<512, 256, 0, stream>>>(V, Lnb, m);
  k_zpart<<<BB * nsc, 192, 0, stream>>>(V, m, zpart, spc, nsc);
  k_final<<<2 * BB, 256, 0, stream>>>(zpart, fw, fb, out, out + BB * CC, nsc);
}